// Round 13
// baseline (2781.087 us; speedup 1.0000x reference)
//
#include <hip/hip_runtime.h>
#include <math.h>

// ---------------------------------------------------------------------------
// observation_processing_network, gfx950.
// R10 2674us (KL 80, 8B exchange).  R11 2072us (KL 64, GAT fusion);
//   k_lanczos 1590us = 198 phases x 8.0us; absmax 0.0117 (det., 1.7x margin)
//   -> K floor reached.
// R12: NB 16->8 (halve barrier-arrival serialization; CH=256, 1 thread/row
//   SpMV); tail fusions: QKV into k_mha, GCN linears into gathers, hm into
//   k_logits, nodeinit into rowptr (17 -> 10 launches).
// ---------------------------------------------------------------------------

#define N    2048
#define NE   131072
#define KL   64
#define TPB  256
#define NB   8
#define CH   (N/NB)      // 256 elements owned per block

#define SIGN1 -1.0f
#define SIGN2 -1.0f

// ---------------- device helpers ----------------
__device__ __forceinline__ unsigned fkey(float f){
  unsigned u = __float_as_uint(f);
  return (u & 0x80000000u) ? ~u : (u | 0x80000000u);
}
__device__ __forceinline__ float fkeyinv(unsigned k){
  unsigned u = (k & 0x80000000u) ? (k ^ 0x80000000u) : ~k;
  return __uint_as_float(u);
}
__device__ __forceinline__ unsigned wang(unsigned s){
  s = (s ^ 61u) ^ (s >> 16); s *= 9u; s ^= s >> 4; s *= 0x27d4eb2du; s ^= s >> 15;
  return s;
}
__device__ __forceinline__ float block_sum(float v, float* sh){
  __syncthreads();
  for (int off = 32; off > 0; off >>= 1) v += __shfl_down(v, off);
  int lane = threadIdx.x & 63, w = threadIdx.x >> 6;
  if (lane == 0) sh[w] = v;
  __syncthreads();
  return sh[0] + sh[1] + sh[2] + sh[3];
}

// ---- agent-scope (LLC-coherent) exchange primitives ----
__device__ __forceinline__ float aloadf(const float* p){
  return __hip_atomic_load(p, __ATOMIC_RELAXED, __HIP_MEMORY_SCOPE_AGENT);
}
__device__ __forceinline__ void astoref(float* p, float v){
  __hip_atomic_store(p, v, __ATOMIC_RELAXED, __HIP_MEMORY_SCOPE_AGENT);
}
__device__ __forceinline__ unsigned aloadu(const unsigned* p){
  return __hip_atomic_load(p, __ATOMIC_RELAXED, __HIP_MEMORY_SCOPE_AGENT);
}
__device__ __forceinline__ int aloadi(const int* p){
  return __hip_atomic_load(p, __ATOMIC_RELAXED, __HIP_MEMORY_SCOPE_AGENT);
}
__device__ __forceinline__ void astorei(int* p, int v){
  __hip_atomic_store(p, v, __ATOMIC_RELAXED, __HIP_MEMORY_SCOPE_AGENT);
}
__device__ __forceinline__ float2 aload2(const float* p){
  unsigned long long v = __hip_atomic_load((const unsigned long long*)p,
                         __ATOMIC_RELAXED, __HIP_MEMORY_SCOPE_AGENT);
  return make_float2(__uint_as_float((unsigned)v),
                     __uint_as_float((unsigned)(v >> 32)));
}
__device__ __forceinline__ void astore2(float* p, float a, float b){
  unsigned long long v = ((unsigned long long)__float_as_uint(b) << 32)
                       | (unsigned long long)__float_as_uint(a);
  __hip_atomic_store((unsigned long long*)p, v,
                     __ATOMIC_RELAXED, __HIP_MEMORY_SCOPE_AGENT);
}

// Fence-free grid barrier (R7-validated). Monotone arrival counter.
__device__ __forceinline__ void gbar(unsigned* cnt, unsigned* gen, unsigned* phase){
  __syncthreads();
  if (threadIdx.x == 0){
    unsigned p = ++(*phase);
    __atomic_signal_fence(__ATOMIC_SEQ_CST);
    __builtin_amdgcn_s_waitcnt(0);
    unsigned old = __hip_atomic_fetch_add(cnt, 1u, __ATOMIC_RELAXED, __HIP_MEMORY_SCOPE_AGENT);
    if (old == p*NB - 1u){
      __hip_atomic_store(gen, p, __ATOMIC_RELAXED, __HIP_MEMORY_SCOPE_AGENT);
    } else {
      while (__hip_atomic_load(gen, __ATOMIC_RELAXED, __HIP_MEMORY_SCOPE_AGENT) < p)
        __builtin_amdgcn_s_sleep(1);
    }
    __atomic_signal_fence(__ATOMIC_SEQ_CST);
  }
  __syncthreads();
}

// ---------------- setup kernels ----------------
__global__ void k_init(float* deg, float* scal, unsigned* bar){
  int i = blockIdx.x*TPB + threadIdx.x;
  if (i < N) deg[i] = 0.f;
  if (i < 16) scal[i] = 0.f;
  if (i < 64) bar[i] = 0u;
}
__global__ void k_deg(const int* ei, float* deg){
  int e = blockIdx.x*TPB + threadIdx.x;
  if (e < NE) atomicAdd(&deg[ei[e]], 1.0f);
}
// rowptr scan + fill + node-wise constants, one 256-thread block
__global__ void k_rowptr(const float* deg, int* rowptr, int* fill,
                         float* dinv, float* d2g, float* v1){
  __shared__ int part[256];
  __shared__ int off[257];
  int t = threadIdx.x;
  int base = t*8;
  int local[8];
  int s = 0;
  for (int k = 0; k < 8; k++){
    int r = base + k;
    float d = deg[r];
    dinv[r] = d > 0.f ? rsqrtf(d) : 0.f;
    d2g[r]  = rsqrtf(d + 1.f);
    v1[r]   = sqrtf(d / (float)NE);
    local[k] = s; s += (int)d;
  }
  part[t] = s;
  __syncthreads();
  if (t == 0){ off[0] = 0; for (int i = 0; i < 256; i++) off[i+1] = off[i] + part[i]; }
  __syncthreads();
  int o = off[t];
  for (int k = 0; k < 8; k++){ int v = o + local[k]; rowptr[base+k] = v; fill[base+k] = v; }
  if (t == 255) rowptr[N] = off[256];
}
__global__ void k_csr(const int* ei, int* fill, int* cols){
  int e = blockIdx.x*TPB + threadIdx.x;
  if (e < NE){
    int s = ei[e];
    int pos = atomicAdd(&fill[s], 1);
    cols[pos] = ei[NE + e];
  }
}

// ---------------- persistent Lanczos + teig + ritz + xc (one launch) -------
__global__ __launch_bounds__(256) void k_lanczos(
    const int* __restrict__ rowptr, const int* __restrict__ cols,
    const float* __restrict__ dinv, const float* __restrict__ v1,
    const float* __restrict__ x,
    float* Qsl, float* yG, float* parts, float* parts2, float* npart,
    float* alpha, float* beta, float* zsm, float* v2, float* xc,
    float* outbuf, float* scal, unsigned* mkv, int* v2i, unsigned* bar){
  __shared__ __align__(16) float ybuf[N];
  __shared__ __align__(16) float yl[CH];
  __shared__ float cb[KL+2], cb2[KL+2];
  __shared__ float npl[NB];
  __shared__ float zl[KL];
  __shared__ float sh[4];
  __shared__ unsigned mkl;
  __shared__ double ta[KL], tb2[KL];
  unsigned* cnt = bar;
  unsigned* gen = bar + 32;
  unsigned phase = 0;
  const int tid = threadIdx.x, blk = blockIdx.x;
  const int base = blk*CH;
  float* Qb = Qsl + (size_t)blk*KL*CH;
  float* ssq = scal + 3;

  // ---- I0: random start slice; v1-dot partial ----
  yl[tid] = (float)(wang(base + tid) & 0xffffffu) * (2.f/16777216.f) - 1.f;
  __syncthreads();
  {
    float p = v1[base + tid]*yl[tid];
    float s = block_sum(p, sh);
    if (tid == 0) astoref(&parts[blk], s);
  }
  gbar(cnt, gen, &phase);
  // ---- I1: deflate v1; norm partial; publish y slice ----
  {
    if (tid < NB) npl[tid] = aloadf(&parts[tid]);
    __syncthreads();
    float c = 0.f;
    for (int b = 0; b < NB; b++) c += npl[b];
    float v = yl[tid] - c*v1[base + tid];
    yl[tid] = v;
    float acc = v*v;
    __syncthreads();
    if (tid < CH/2) astore2(yG + base + 2*tid, yl[2*tid], yl[2*tid+1]);
    float s = block_sum(acc, sh);
    if (tid == 0) astoref(&npart[blk], s);
  }
  gbar(cnt, gen, &phase);

  for (int j = 0; j < KL; j++){
    // ---- P0: stage y + npart; rn; beta; SpMV (1 thread/row); Q[j]; dots-a
    {
      for (int t = tid; t < N/2; t += TPB){
        float2 v = aload2(yG + 2*t);
        ybuf[2*t] = v.x; ybuf[2*t+1] = v.y;
      }
      if (tid < NB/2){
        float2 v = aload2(npart + 2*tid);
        npl[2*tid] = v.x; npl[2*tid+1] = v.y;
      }
    }
    __syncthreads();
    {
      float ss = 0.f;
      for (int b = 0; b < NB; b++) ss += npl[b];
      float rn = rsqrtf(ss);
      if (blk == 0 && tid == 0 && j > 0) beta[j-1] = sqrtf(ss);
      int row = base + tid;
      int b0 = rowptr[row], b1 = rowptr[row+1];
      float sg = 0.f;
      for (int p = b0; p < b1; p++){
        int c = cols[p];
        sg += dinv[c]*ybuf[c];
      }
      float q = rn*ybuf[row];
      Qb[(size_t)j*CH + tid] = q;
      yl[tid] = q - dinv[row]*rn*sg;
    }
    __syncthreads();
    if (tid <= j+1){
      float d = 0.f;
      const float4* y4 = (const float4*)yl;
      if (tid <= j){
        const float4* q4 = (const float4*)(Qb + (size_t)tid*CH);
        for (int e = 0; e < CH/4; e++){
          float4 q = q4[e], yv = y4[e];
          d += q.x*yv.x + q.y*yv.y + q.z*yv.z + q.w*yv.w;
        }
      } else {
        const float4* v4 = (const float4*)(v1 + base);
        for (int e = 0; e < CH/4; e++){
          float4 q = v4[e], yv = y4[e];
          d += q.x*yv.x + q.y*yv.y + q.z*yv.z + q.w*yv.w;
        }
      }
      astoref(&parts[tid*NB + blk], d);
    }
    gbar(cnt, gen, &phase);
    // ---- P1: cb = rowsum(parts); sub-a (elem/thread); dots-b ----
    if (tid <= j+1){
      const float* pr = parts + tid*NB;
      float s = 0.f;
      for (int b = 0; b < NB/2; b++){
        float2 v = aload2(pr + 2*b);
        s += v.x + v.y;
      }
      cb[tid] = s;
    }
    __syncthreads();
    {
      float a2 = 0.f;
      for (int i = 0; i <= j; i++) a2 += cb[i]*Qb[(size_t)i*CH + tid];
      a2 += cb[j+1]*v1[base + tid];
      yl[tid] -= a2;
    }
    __syncthreads();
    if (tid <= j+1){
      float d = 0.f;
      const float4* y4 = (const float4*)yl;
      if (tid <= j){
        const float4* q4 = (const float4*)(Qb + (size_t)tid*CH);
        for (int e = 0; e < CH/4; e++){
          float4 q = q4[e], yv = y4[e];
          d += q.x*yv.x + q.y*yv.y + q.z*yv.z + q.w*yv.w;
        }
      } else {
        const float4* v4 = (const float4*)(v1 + base);
        for (int e = 0; e < CH/4; e++){
          float4 q = v4[e], yv = y4[e];
          d += q.x*yv.x + q.y*yv.y + q.z*yv.z + q.w*yv.w;
        }
      }
      astoref(&parts2[tid*NB + blk], d);
    }
    gbar(cnt, gen, &phase);
    // ---- P2: cb2 = rowsum(parts2); alpha; sub-b; norm; publish y ----
    if (tid <= j+1){
      const float* pr = parts2 + tid*NB;
      float s = 0.f;
      for (int b = 0; b < NB/2; b++){
        float2 v = aload2(pr + 2*b);
        s += v.x + v.y;
      }
      cb2[tid] = s;
    }
    __syncthreads();
    if (blk == 0 && tid == j) alpha[j] = cb[j] + cb2[j];
    float nv;
    {
      float a2 = 0.f;
      for (int i = 0; i <= j; i++) a2 += cb2[i]*Qb[(size_t)i*CH + tid];
      a2 += cb2[j+1]*v1[base + tid];
      float v = yl[tid] - a2;
      yl[tid] = v;
      nv = v*v;
    }
    float s = block_sum(nv, sh);
    if (tid == 0) astoref(&npart[blk], s);
    if (tid < CH/2) astore2(yG + base + 2*tid, yl[2*tid], yl[2*tid+1]);
    gbar(cnt, gen, &phase);
  }

  // ---- tail: tridiagonal eig (block 0) ----
  const int wid = tid >> 6, lane = tid & 63;
  if (blk == 0){
    for (int i = tid; i < KL; i += TPB) ta[i] = (double)alpha[i];
    for (int i = tid; i < KL-1; i += TPB){ double bb = (double)beta[i]; tb2[i] = bb*bb; }
    __syncthreads();
    if (wid == 0){
      double th[2];
      for (int k = 1; k <= 2; k++){
        double lo = -0.5, hi = 2.5;
        for (int r = 0; r < 5; r++){
          double xx = lo + (hi - lo)*(double)(lane + 1)/65.0;
          int c = 0; double q = 1.0;
          for (int i = 0; i < KL; i++){
            double t = ta[i] - xx - ((i > 0) ? tb2[i-1]/q : 0.0);
            if (t == 0.0) t = -1e-300;
            if (t < 0.0) c++;
            q = t;
          }
          unsigned long long m = __ballot(c >= k);
          if (m == 0ULL){
            lo = lo + (hi - lo)*(64.0/65.0);
          } else {
            int f = __ffsll((long long)m) - 1;
            double nhi = lo + (hi - lo)*(double)(f + 1)/65.0;
            double nlo = lo + (hi - lo)*(double)f/65.0;
            hi = nhi; lo = nlo;
          }
        }
        th[k-1] = 0.5*(lo + hi);
      }
      double theta = (th[0] < 0.25) ? th[1] : th[0];
      if (lane == 0){
        double d[KL], dl[KL], du[KL], du2[KL], xv[KL];
        int ip[KL];
        for (int i = 0; i < KL; i++) d[i] = ta[i] - theta;
        for (int i = 0; i < KL-1; i++){ double b = (double)beta[i]; dl[i] = b; du[i] = b; }
        for (int i = 0; i < KL-1; i++){
          if (fabs(d[i]) >= fabs(dl[i])){
            ip[i] = 0;
            if (d[i] == 0.0) d[i] = 1e-30;
            double f = dl[i]/d[i]; dl[i] = f; d[i+1] -= f*du[i];
            if (i < KL-2) du2[i] = 0.0;
          } else {
            double f = d[i]/dl[i];
            d[i] = dl[i]; dl[i] = f;
            double t = du[i]; du[i] = d[i+1]; d[i+1] = t - f*d[i+1];
            if (i < KL-2){ du2[i] = du[i+1]; du[i+1] = -f*du[i+1]; }
            ip[i] = 1;
          }
        }
        if (d[KL-1] == 0.0) d[KL-1] = 1e-30;
        for (int i = 0; i < KL; i++) xv[i] = (double)(wang(1000u + i) & 0xffffu)/65536.0 - 0.5;
        for (int it = 0; it < 4; it++){
          for (int i = 0; i < KL-1; i++){
            if (ip[i] == 0) xv[i+1] -= dl[i]*xv[i];
            else { double t = xv[i]; xv[i] = xv[i+1]; xv[i+1] = t - dl[i]*xv[i]; }
          }
          xv[KL-1] /= d[KL-1];
          xv[KL-2] = (xv[KL-2] - du[KL-2]*xv[KL-1])/d[KL-2];
          for (int i = KL-3; i >= 0; i--) xv[i] = (xv[i] - du[i]*xv[i+1] - du2[i]*xv[i+2])/d[i];
          double m = 0.0;
          for (int i = 0; i < KL; i++) m = fmax(m, fabs(xv[i]));
          if (m > 0.0) for (int i = 0; i < KL; i++) xv[i] /= m;
        }
        double nrm = 0.0;
        for (int i = 0; i < KL; i++) nrm += xv[i]*xv[i];
        nrm = sqrt(nrm);
        for (int i = 0; i < KL; i++) astoref(&zsm[i], (float)(xv[i]/nrm));
      }
    }
  }
  gbar(cnt, gen, &phase);
  // ---- ritz + stats ----
  if (tid < KL) zl[tid] = aloadf(&zsm[tid]);
  __syncthreads();
  float a = 0.f;
  for (int i = 0; i < KL; i++) a += zl[i]*Qb[(size_t)i*CH + tid];
  astoref(&v2[base + tid], a);
  {
    float sq = block_sum(a*a, sh);
    __syncthreads();
    float av = fabsf(a);
    for (int d2 = 1; d2 < 64; d2 <<= 1) av = fmaxf(av, __shfl_xor(av, d2));
    if ((tid & 63) == 0) sh[tid >> 6] = av;
    __syncthreads();
    if (tid == 0){
      float mb = fmaxf(fmaxf(sh[0], sh[1]), fmaxf(sh[2], sh[3]));
      atomicAdd(ssq, sq);
      atomicMax(mkv, fkey(mb));
      if (blk == 0) astorei(v2i, N);
    }
  }
  gbar(cnt, gen, &phase);
  // ---- idx of max |v2| ----
  if (tid == 0) mkl = aloadu(mkv);
  __syncthreads();
  {
    float vv = aloadf(&v2[base + tid]);
    if (fkey(fabsf(vv)) == mkl) atomicMin(v2i, base + tid);
  }
  gbar(cnt, gen, &phase);
  // ---- sign/scale factor ----
  if (blk == 0 && tid == 0){
    float s = rsqrtf(aloadf(ssq));
    int ii = aloadi(v2i);
    if (aloadf(&v2[ii]) < 0.f) s = -s;
    astoref(&scal[4], SIGN2 * s);
  }
  gbar(cnt, gen, &phase);
  // ---- scale v2; write xc and output-2 ----
  {
    int i = base + tid;
    float sc = aloadf(&scal[4]);
    float l1 = aloadf(&v2[i])*sc;
    float l0 = SIGN1*v1[i];
    float c0 = x[i*3+0], c1 = x[i*3+1], c2 = x[i*3+2];
    float* xr = xc + (size_t)i*5;
    xr[0]=c0; xr[1]=c1; xr[2]=c2; xr[3]=l0; xr[4]=l1;
    float* o = outbuf + (size_t)N*N + 1 + (size_t)i*5;
    o[0]=c0; o[1]=c1; o[2]=c2; o[3]=l0; o[4]=l1;
  }
}

// ---------------- fused GAT layer: lin + attention scores + gather ---------
__global__ __launch_bounds__(256) void k_gat_fused(
    const int* __restrict__ rowptr, const int* __restrict__ cols,
    const float* __restrict__ in, const float* __restrict__ W,
    const float* __restrict__ as, const float* __restrict__ adp,
    const float* __restrict__ bias, float* hout, int Fin, int F, int act){
  int row = blockIdx.x*4 + (threadIdx.x >> 6);
  int lane = threadIdx.x & 63;
  int b0 = rowptr[row], b1 = rowptr[row+1];
  float hwr[8];
  {
    const float* ir = in + (size_t)row*Fin;
    for (int f = 0; f < F; f++){
      float acc = 0.f;
      for (int k = 0; k < Fin; k++) acc += ir[k]*W[k*F+f];
      hwr[f] = acc;
    }
  }
  float adv = 0.f, alr = 0.f;
  for (int f = 0; f < F; f++){ adv += hwr[f]*adp[f]; alr += hwr[f]*as[f]; }
  float es = alr + adv; es = es >= 0.f ? es : 0.2f*es;
  float m = es;
  for (int p = b0 + lane; p < b1; p += 64){
    const float* ic = in + (size_t)cols[p]*Fin;
    float al = 0.f;
    for (int f = 0; f < F; f++){
      float acc = 0.f;
      for (int k = 0; k < Fin; k++) acc += ic[k]*W[k*F+f];
      al += acc*as[f];
    }
    float e = al + adv; e = e >= 0.f ? e : 0.2f*e;
    m = fmaxf(m, e);
  }
  for (int d = 1; d < 64; d <<= 1) m = fmaxf(m, __shfl_xor(m, d));
  float Z = 0.f;
  float accf[8];
  for (int f = 0; f < 8; f++) accf[f] = 0.f;
  for (int p = b0 + lane; p < b1; p += 64){
    const float* ic = in + (size_t)cols[p]*Fin;
    float hc[8];
    float al = 0.f;
    for (int f = 0; f < F; f++){
      float acc = 0.f;
      for (int k = 0; k < Fin; k++) acc += ic[k]*W[k*F+f];
      hc[f] = acc;
      al += acc*as[f];
    }
    float e = al + adv; e = e >= 0.f ? e : 0.2f*e;
    float w = expf(e - m);
    Z += w;
    for (int f = 0; f < F; f++) accf[f] += w*hc[f];
  }
  if (lane == 0){
    float w = expf(es - m);
    Z += w;
    for (int f = 0; f < F; f++) accf[f] += w*hwr[f];
  }
  for (int d = 1; d < 64; d <<= 1){
    Z += __shfl_xor(Z, d);
    for (int f = 0; f < F; f++) accf[f] += __shfl_xor(accf[f], d);
  }
  if (lane < F){
    float v = accf[lane]/(Z + 1e-16f) + bias[lane];
    if (act) v = fmaxf(v, 0.f);
    hout[(size_t)row*F + lane] = v;
  }
}

// ---------------- fused MHA: q/k/v on the fly (seq=2048, d=5) --------------
__global__ __launch_bounds__(256) void k_mha_f(const float* __restrict__ h2,
    const float* __restrict__ Wq, const float* __restrict__ bq,
    const float* __restrict__ Wk, const float* __restrict__ bk,
    const float* __restrict__ Wv, const float* __restrict__ bv, float* av){
  __shared__ float s[N];
  __shared__ float sh[4];
  __shared__ float red[4];
  int i = blockIdx.x;
  float q[5];
  {
    const float* hr = h2 + (size_t)i*5;
    for (int f = 0; f < 5; f++){
      float acc = bq[f];
      for (int k = 0; k < 5; k++) acc += hr[k]*Wq[k*5+f];
      q[f] = acc;
    }
  }
  float wk[25], wv[25], bkr[5], bvr[5];
  for (int t = 0; t < 25; t++){ wk[t] = Wk[t]; wv[t] = Wv[t]; }
  for (int t = 0; t < 5; t++){ bkr[t] = bk[t]; bvr[t] = bv[t]; }
  float lmax = -1e30f;
  for (int j = threadIdx.x; j < N; j += TPB){
    const float* hr = h2 + (size_t)j*5;
    float h0=hr[0], h1=hr[1], h2v=hr[2], h3v=hr[3], h4=hr[4];
    float sc = 0.f;
    for (int f = 0; f < 5; f++){
      float kf = bkr[f] + h0*wk[f] + h1*wk[5+f] + h2v*wk[10+f] + h3v*wk[15+f] + h4*wk[20+f];
      sc += q[f]*kf;
    }
    sc *= 0.44721360f;
    s[j] = sc;
    lmax = fmaxf(lmax, sc);
  }
  for (int off = 32; off > 0; off >>= 1) lmax = fmaxf(lmax, __shfl_down(lmax, off));
  int lane = threadIdx.x & 63, w = threadIdx.x >> 6;
  if (lane == 0) red[w] = lmax;
  __syncthreads();
  float m = fmaxf(fmaxf(red[0], red[1]), fmaxf(red[2], red[3]));
  float Zp = 0.f, a0=0.f, a1=0.f, a2=0.f, a3=0.f, a4=0.f;
  for (int j = threadIdx.x; j < N; j += TPB){
    float p = expf(s[j] - m);
    const float* hr = h2 + (size_t)j*5;
    float h0=hr[0], h1=hr[1], h2v=hr[2], h3v=hr[3], h4=hr[4];
    Zp += p;
    a0 += p*(bvr[0] + h0*wv[0] + h1*wv[5]  + h2v*wv[10] + h3v*wv[15] + h4*wv[20]);
    a1 += p*(bvr[1] + h0*wv[1] + h1*wv[6]  + h2v*wv[11] + h3v*wv[16] + h4*wv[21]);
    a2 += p*(bvr[2] + h0*wv[2] + h1*wv[7]  + h2v*wv[12] + h3v*wv[17] + h4*wv[22]);
    a3 += p*(bvr[3] + h0*wv[3] + h1*wv[8]  + h2v*wv[13] + h3v*wv[18] + h4*wv[23]);
    a4 += p*(bvr[4] + h0*wv[4] + h1*wv[9]  + h2v*wv[14] + h3v*wv[19] + h4*wv[24]);
  }
  float Z  = block_sum(Zp, sh);
  float A0 = block_sum(a0, sh);
  float A1 = block_sum(a1, sh);
  float A2 = block_sum(a2, sh);
  float A3 = block_sum(a3, sh);
  float A4 = block_sum(a4, sh);
  if (threadIdx.x == 0){
    float inv = 1.f/Z;
    float* o = av + (size_t)i*5;
    o[0]=A0*inv; o[1]=A1*inv; o[2]=A2*inv; o[3]=A3*inv; o[4]=A4*inv;
  }
}

// fused: h3 = attnout@Wo+bo, then tq/tk/tv = h3@Wt*+bt* (one thread/node)
__global__ void k_h3tc(const float* att, const float* Wo, const float* bo,
                       const float* Wtq, const float* btq,
                       const float* Wtk, const float* btk,
                       const float* Wtv, const float* btv,
                       float* h3, float* tq, float* tk, float* tv){
  int i = blockIdx.x*TPB + threadIdx.x;
  if (i >= N) return;
  const float* ar = att + (size_t)i*5;
  float h[5];
  for (int f = 0; f < 5; f++){
    float acc = bo[f];
    for (int k = 0; k < 5; k++) acc += ar[k]*Wo[k*5+f];
    h[f] = acc;
  }
  float* hr = h3 + (size_t)i*5;
  float* qr = tq + (size_t)i*5;
  float* kr = tk + (size_t)i*5;
  float* vr = tv + (size_t)i*5;
  for (int f = 0; f < 5; f++){
    float aq = btq[f], ak = btk[f], av = btv[f];
    for (int k = 0; k < 5; k++){
      float hk = h[k];
      aq += hk*Wtq[k*5+f]; ak += hk*Wtk[k*5+f]; av += hk*Wtv[k*5+f];
    }
    hr[f] = h[f]; qr[f] = aq; kr[f] = ak; vr[f] = av;
  }
}

// ---------------- TransformerConv row-gather + root skip -------------------
__global__ __launch_bounds__(256) void k_tc_gather(
    const int* __restrict__ rowptr, const int* __restrict__ cols,
    const float* __restrict__ tq, const float* __restrict__ tk,
    const float* __restrict__ tv, const float* __restrict__ h3,
    const float* __restrict__ Wts, const float* __restrict__ bts, float* xt){
  int row = blockIdx.x*4 + (threadIdx.x >> 6);
  int lane = threadIdx.x & 63;
  int b0 = rowptr[row], b1 = rowptr[row+1];
  const float* qr = tq + (size_t)row*5;
  float q0=qr[0], q1=qr[1], q2=qr[2], q3=qr[3], q4=qr[4];
  const float* ks = tk + (size_t)row*5;
  float es = (q0*ks[0]+q1*ks[1]+q2*ks[2]+q3*ks[3]+q4*ks[4])*0.44721360f;
  float m = es;
  for (int p = b0 + lane; p < b1; p += 64){
    const float* kr = tk + (size_t)cols[p]*5;
    float e = (q0*kr[0]+q1*kr[1]+q2*kr[2]+q3*kr[3]+q4*kr[4])*0.44721360f;
    m = fmaxf(m, e);
  }
  for (int d = 1; d < 64; d <<= 1) m = fmaxf(m, __shfl_xor(m, d));
  float Z = 0.f;
  float accf[5];
  for (int f = 0; f < 5; f++) accf[f] = 0.f;
  for (int p = b0 + lane; p < b1; p += 64){
    int c = cols[p];
    const float* kr = tk + (size_t)c*5;
    float e = (q0*kr[0]+q1*kr[1]+q2*kr[2]+q3*kr[3]+q4*kr[4])*0.44721360f;
    float w = expf(e - m);
    Z += w;
    const float* vr = tv + (size_t)c*5;
    for (int f = 0; f < 5; f++) accf[f] += w*vr[f];
  }
  if (lane == 0){
    float w = expf(es - m);
    Z += w;
    const float* vr = tv + (size_t)row*5;
    for (int f = 0; f < 5; f++) accf[f] += w*vr[f];
  }
  for (int d = 1; d < 64; d <<= 1){
    Z += __shfl_xor(Z, d);
    for (int f = 0; f < 5; f++) accf[f] += __shfl_xor(accf[f], d);
  }
  if (lane < 5){
    const float* hr = h3 + (size_t)row*5;
    float skip = bts[lane];
    for (int k2 = 0; k2 < 5; k2++) skip += hr[k2]*Wts[k2*5 + lane];
    xt[(size_t)row*5 + lane] = accf[lane]/(Z + 1e-16f) + skip;
  }
}

// ---------------- GCN row-gathers with fused input linears -----------------
// z16 = relu(Ahat @ (xt@Wg1) + bg1); P16 computed on the fly per edge.
__global__ __launch_bounds__(256) void k_gcn16f(
    const int* __restrict__ rowptr, const int* __restrict__ cols,
    const float* __restrict__ xt, const float* __restrict__ Wg1,
    const float* __restrict__ d2g, const float* __restrict__ bg1, float* z16){
  __shared__ float wg[80];
  if (threadIdx.x < 80) wg[threadIdx.x] = Wg1[threadIdx.x];
  __syncthreads();
  int row = blockIdx.x*4 + (threadIdx.x >> 6);
  int lane = threadIdx.x & 63;
  int b0 = rowptr[row], b1 = rowptr[row+1];
  float dr = d2g[row];
  float acc[16];
  for (int f = 0; f < 16; f++) acc[f] = 0.f;
  for (int p = b0 + lane; p < b1; p += 64){
    int c = cols[p];
    float w = d2g[c];
    const float* xr = xt + (size_t)c*5;
    float x0=xr[0], x1=xr[1], x2=xr[2], x3=xr[3], x4=xr[4];
    for (int f = 0; f < 16; f++)
      acc[f] += w*(x0*wg[f] + x1*wg[16+f] + x2*wg[32+f] + x3*wg[48+f] + x4*wg[64+f]);
  }
  if (lane == 0){
    const float* xr = xt + (size_t)row*5;
    float x0=xr[0], x1=xr[1], x2=xr[2], x3=xr[3], x4=xr[4];
    for (int f = 0; f < 16; f++)
      acc[f] += dr*(x0*wg[f] + x1*wg[16+f] + x2*wg[32+f] + x3*wg[48+f] + x4*wg[64+f]);
  }
  for (int d = 1; d < 64; d <<= 1)
    for (int f = 0; f < 16; f++) acc[f] += __shfl_xor(acc[f], d);
  if (lane < 16)
    z16[(size_t)row*16 + lane] = fmaxf(dr*acc[lane] + bg1[lane], 0.f);
}
// u = Ahat @ (z16@Wg2) + bg2; p1 on the fly per edge.
__global__ __launch_bounds__(256) void k_gcn1f(
    const int* __restrict__ rowptr, const int* __restrict__ cols,
    const float* __restrict__ z16, const float* __restrict__ Wg2,
    const float* __restrict__ d2g, const float* __restrict__ bg2,
    float* u, unsigned* mku, int* crit){
  __shared__ float wg[16];
  if (threadIdx.x < 16) wg[threadIdx.x] = Wg2[threadIdx.x];
  __syncthreads();
  int row = blockIdx.x*4 + (threadIdx.x >> 6);
  int lane = threadIdx.x & 63;
  if (blockIdx.x == 0 && threadIdx.x == 0) crit[0] = N;
  int b0 = rowptr[row], b1 = rowptr[row+1];
  float s = 0.f;
  for (int p = b0 + lane; p < b1; p += 64){
    int c = cols[p];
    const float* zr = z16 + (size_t)c*16;
    float p1c = 0.f;
    for (int k = 0; k < 16; k++) p1c += zr[k]*wg[k];
    s += d2g[c]*p1c;
  }
  if (lane == 0){
    const float* zr = z16 + (size_t)row*16;
    float p1c = 0.f;
    for (int k = 0; k < 16; k++) p1c += zr[k]*wg[k];
    s += d2g[row]*p1c;
  }
  for (int d = 1; d < 64; d <<= 1) s += __shfl_xor(s, d);
  float uv = d2g[row]*s + bg2[0];
  if (lane == 0){
    u[row] = uv;
    atomicMax(mku, fkey(uv));
  }
}
__global__ void k_crit(const float* u, const unsigned* mk, int* crit, float* bonus){
  int i = blockIdx.x*TPB + threadIdx.x;
  if (i == 0){
    float um = fkeyinv(mk[0]);
    bonus[0] = ((0.8f - um) < 0.2f) ? 10.f : 0.f;
  }
  if (i >= N) return;
  if (u[i] == fkeyinv(mk[0])) atomicMin(crit, i);
}

// ---------------- final logits + value (hm fused in LDS) -------------------
__global__ __launch_bounds__(256) void k_logits(const float* xt,
    const float* W1, const float* b1, const float* W2,
    const float* b2, const float* mask, const float* Wc, const int* crit,
    const float* bonus, float* out, float* vacc){
  __shared__ float sh[4];
  __shared__ float hml[64];
  int i = blockIdx.y;
  if (threadIdx.x < 64){
    const float* xr = xt + (size_t)i*5;
    float acc = b1[threadIdx.x];
    for (int k = 0; k < 5; k++) acc += xr[k]*W1[k*64 + threadIdx.x];
    hml[threadIdx.x] = fmaxf(acc, 0.f);
  }
  __syncthreads();
  int j = blockIdx.x*TPB + threadIdx.x;
  float acc = b2[j];
  for (int c = 0; c < 64; c++) acc += hml[c]*W2[c*N + j];
  if (i == crit[0]) acc += bonus[0];
  out[(size_t)i*N + j] = acc*mask[j];
  float s = block_sum(acc*Wc[j], sh);
  if (threadIdx.x == 0) atomicAdd(vacc, s);
}
__global__ void k_value(const float* vacc, const float* bc, float* out){
  out[(size_t)N*N] = vacc[0]/(float)N + bc[0];
}

// ---------------------------------------------------------------------------
extern "C" void kernel_launch(void* const* d_in, const int* in_sizes, int n_in,
                              void* d_out, int out_size, void* d_ws, size_t ws_size,
                              hipStream_t stream){
  const float* x    = (const float*)d_in[0];
  const int*   ei   = (const int*)d_in[1];
  const float* mask = (const float*)d_in[2];
  const float* Wg1=(const float*)d_in[3];  const float* bg1=(const float*)d_in[4];
  const float* Wg2=(const float*)d_in[5];  const float* bg2=(const float*)d_in[6];
  const float* Wa1=(const float*)d_in[7];  const float* as1=(const float*)d_in[8];
  const float* ad1=(const float*)d_in[9];  const float* ba1=(const float*)d_in[10];
  const float* Wa2=(const float*)d_in[11]; const float* as2=(const float*)d_in[12];
  const float* ad2=(const float*)d_in[13]; const float* ba2=(const float*)d_in[14];
  const float* Wq=(const float*)d_in[15];  const float* bq=(const float*)d_in[16];
  const float* Wk=(const float*)d_in[17];  const float* bk=(const float*)d_in[18];
  const float* Wv=(const float*)d_in[19];  const float* bv=(const float*)d_in[20];
  const float* Wo=(const float*)d_in[21];  const float* bo=(const float*)d_in[22];
  const float* Wtq=(const float*)d_in[23]; const float* btq=(const float*)d_in[24];
  const float* Wtk=(const float*)d_in[25]; const float* btk=(const float*)d_in[26];
  const float* Wtv=(const float*)d_in[27]; const float* btv=(const float*)d_in[28];
  const float* Wts=(const float*)d_in[29]; const float* bts=(const float*)d_in[30];
  const float* W1=(const float*)d_in[31];  const float* b1=(const float*)d_in[32];
  const float* W2=(const float*)d_in[33];  const float* b2=(const float*)d_in[34];
  const float* Wc=(const float*)d_in[35];  const float* bc=(const float*)d_in[36];
  float* out = (float*)d_out;
  float* ws  = (float*)d_ws;

  // ---- ws layout (floats) ----
  float* deg  = ws;           float* dinv = ws + 2048;
  float* d2g  = ws + 4096;    float* v1   = ws + 6144;
  float* y    = ws + 8192;    float* v2   = ws + 10240;
  float* alpha= ws + 12448;   float* beta = ws + 12576;
  float* scal = ws + 12704;                        // 16 scalar slots
  unsigned* mku = (unsigned*)(scal + 8);
  unsigned* mkv = (unsigned*)(scal + 9);
  int* crit = (int*)(scal + 10);
  int* v2i  = (int*)(scal + 11);
  float* zsm  = ws + 12720;                        // 128
  float* h2   = ws + 21040;
  float* h3   = ws + 62000;   float* tqb  = ws + 72240;
  float* tkb  = ws + 82480;   float* tvb  = ws + 92720;
  float* xt   = ws + 102960;
  float* u    = ws + 115248;

  // ---- big scratch carved from d_out[0..N*N): consumed before k_logits ----
  float* Qsl  = out;                    // NB*KL*CH = 131072
  float* hw   = out + 262144;           // 16384 (MHA attn out)
  float* h8   = out + 278528;           // 16384
  float* z16  = out + 327680;           // 32768
  float* xc   = out + 360448;           // 10240
  unsigned* bar = (unsigned*)(out + 370688);  // 64
  int* rowptr = (int*)(out + 370752);   // 2049
  int* fill   = (int*)(out + 372864);   // 2048
  int* cols   = (int*)(out + 374912);   // 131072 -> ends 505984
  float* parts  = out + 507904;
  float* parts2 = out + 510080;
  float* npart  = out + 512256;

  // ================= setup =================
  k_init<<<8, TPB, 0, stream>>>(deg, scal, bar);
  k_deg<<<NE/TPB, TPB, 0, stream>>>(ei, deg);
  k_rowptr<<<1, TPB, 0, stream>>>(deg, rowptr, fill, dinv, d2g, v1);
  k_csr<<<NE/TPB, TPB, 0, stream>>>(ei, fill, cols);

  // ================= Lanczos + teig + ritz + xc (one launch) ===============
  k_lanczos<<<NB, TPB, 0, stream>>>(rowptr, cols, dinv, v1, x, Qsl, y,
                                    parts, parts2, npart, alpha, beta, zsm,
                                    v2, xc, out, scal, mkv, v2i, bar);

  const int gRow = N/4;

  // ================= GAT layers (fused lin+scores+gather) =================
  k_gat_fused<<<gRow, TPB, 0, stream>>>(rowptr, cols, xc, Wa1, as1, ad1, ba1, h8, 5, 8, 1);
  k_gat_fused<<<gRow, TPB, 0, stream>>>(rowptr, cols, h8, Wa2, as2, ad2, ba2, h2, 8, 5, 0);

  // ================= MultiheadAttention (qkv fused) + TC projections ======
  k_mha_f<<<N, TPB, 0, stream>>>(h2, Wq, bq, Wk, bk, Wv, bv, hw);
  k_h3tc<<<8, TPB, 0, stream>>>(hw, Wo, bo, Wtq, btq, Wtk, btk, Wtv, btv,
                                h3, tqb, tkb, tvb);

  // ================= TransformerConv (fused skip) =================
  k_tc_gather<<<gRow, TPB, 0, stream>>>(rowptr, cols, tqb, tkb, tvb, h3, Wts, bts, xt);

  // ================= GCN uncertainty net (linears fused into gathers) =====
  k_gcn16f<<<gRow, TPB, 0, stream>>>(rowptr, cols, xt, Wg1, d2g, bg1, z16);
  k_gcn1f<<<gRow, TPB, 0, stream>>>(rowptr, cols, z16, Wg2, d2g, bg2, u, mku, crit);
  k_crit<<<8, TPB, 0, stream>>>(u, mku, crit, scal + 5);

  // ================= logits (hm fused) + value =================
  k_logits<<<dim3(8, N), TPB, 0, stream>>>(xt, W1, b1, W2, b2, mask, Wc, crit,
                                           scal + 5, out, scal + 6);
  k_value<<<1, 1, 0, stream>>>(scal + 6, bc, out);
}

// Round 15
// 2501.998 us; speedup vs baseline: 1.1115x; 1.1115x over previous
//
#include <hip/hip_runtime.h>
#include <math.h>

// ---------------------------------------------------------------------------
// observation_processing_network, gfx950.
// R11 2072us (best passing).  R12 2781us NB=8 regression (reverted).
// R13 FAILED: xtp was carved from d_out[0..N^2) and k_logits read it while
//   concurrently writing all logits rows -> race corrupted rows' hm inputs
//   (output0 ~= stub level 4.57e-2 = max|ref|).  Mega-kernel itself OK.
// R14: xtp moved to ws (race-free).  Otherwise identical to R13: Lanczos +
//   GAT1/GAT2/MHA/TC/GCN16/GCN1/crit as phases of ONE persistent kernel
//   (fence-free barriers, 8B agent exchange, softmax max-skip), 7 launches.
// ---------------------------------------------------------------------------

#define N    2048
#define NE   131072
#define KL   64
#define TPB  256
#define NB   16
#define CH   (N/NB)      // 128 rows owned per block

#define SIGN1 -1.0f
#define SIGN2 -1.0f

// ---------------- device helpers ----------------
__device__ __forceinline__ unsigned fkey(float f){
  unsigned u = __float_as_uint(f);
  return (u & 0x80000000u) ? ~u : (u | 0x80000000u);
}
__device__ __forceinline__ float fkeyinv(unsigned k){
  unsigned u = (k & 0x80000000u) ? (k ^ 0x80000000u) : ~k;
  return __uint_as_float(u);
}
__device__ __forceinline__ unsigned wang(unsigned s){
  s = (s ^ 61u) ^ (s >> 16); s *= 9u; s ^= s >> 4; s *= 0x27d4eb2du; s ^= s >> 15;
  return s;
}
__device__ __forceinline__ float block_sum(float v, float* sh){
  __syncthreads();
  for (int off = 32; off > 0; off >>= 1) v += __shfl_down(v, off);
  int lane = threadIdx.x & 63, w = threadIdx.x >> 6;
  if (lane == 0) sh[w] = v;
  __syncthreads();
  return sh[0] + sh[1] + sh[2] + sh[3];
}
__device__ __forceinline__ float wred(float v){
  for (int d = 1; d < 64; d <<= 1) v += __shfl_xor(v, d);
  return v;
}

// ---- agent-scope (LLC-coherent) exchange primitives ----
__device__ __forceinline__ float aloadf(const float* p){
  return __hip_atomic_load(p, __ATOMIC_RELAXED, __HIP_MEMORY_SCOPE_AGENT);
}
__device__ __forceinline__ void astoref(float* p, float v){
  __hip_atomic_store(p, v, __ATOMIC_RELAXED, __HIP_MEMORY_SCOPE_AGENT);
}
__device__ __forceinline__ unsigned aloadu(const unsigned* p){
  return __hip_atomic_load(p, __ATOMIC_RELAXED, __HIP_MEMORY_SCOPE_AGENT);
}
__device__ __forceinline__ int aloadi(const int* p){
  return __hip_atomic_load(p, __ATOMIC_RELAXED, __HIP_MEMORY_SCOPE_AGENT);
}
__device__ __forceinline__ void astorei(int* p, int v){
  __hip_atomic_store(p, v, __ATOMIC_RELAXED, __HIP_MEMORY_SCOPE_AGENT);
}
__device__ __forceinline__ float2 aload2(const float* p){
  unsigned long long v = __hip_atomic_load((const unsigned long long*)p,
                         __ATOMIC_RELAXED, __HIP_MEMORY_SCOPE_AGENT);
  return make_float2(__uint_as_float((unsigned)v),
                     __uint_as_float((unsigned)(v >> 32)));
}
__device__ __forceinline__ void astore2(float* p, float a, float b){
  unsigned long long v = ((unsigned long long)__float_as_uint(b) << 32)
                       | (unsigned long long)__float_as_uint(a);
  __hip_atomic_store((unsigned long long*)p, v,
                     __ATOMIC_RELAXED, __HIP_MEMORY_SCOPE_AGENT);
}
// 5-float row load from a stride-8 published buffer
__device__ __forceinline__ void aload5(const float* p, float* r){
  float2 a = aload2(p), b = aload2(p+2);
  r[0]=a.x; r[1]=a.y; r[2]=b.x; r[3]=b.y; r[4]=aloadf(p+4);
}

// Fence-free grid barrier (R7-validated). Monotone arrival counter.
__device__ __forceinline__ void gbar(unsigned* cnt, unsigned* gen, unsigned* phase){
  __syncthreads();
  if (threadIdx.x == 0){
    unsigned p = ++(*phase);
    __atomic_signal_fence(__ATOMIC_SEQ_CST);
    __builtin_amdgcn_s_waitcnt(0);
    unsigned old = __hip_atomic_fetch_add(cnt, 1u, __ATOMIC_RELAXED, __HIP_MEMORY_SCOPE_AGENT);
    if (old == p*NB - 1u){
      __hip_atomic_store(gen, p, __ATOMIC_RELAXED, __HIP_MEMORY_SCOPE_AGENT);
    } else {
      while (__hip_atomic_load(gen, __ATOMIC_RELAXED, __HIP_MEMORY_SCOPE_AGENT) < p)
        __builtin_amdgcn_s_sleep(1);
    }
    __atomic_signal_fence(__ATOMIC_SEQ_CST);
  }
  __syncthreads();
}

// ---------------- setup kernels ----------------
__global__ void k_init(float* deg, float* scal, unsigned* bar){
  int i = blockIdx.x*TPB + threadIdx.x;
  if (i < N) deg[i] = 0.f;
  if (i < 16) scal[i] = 0.f;
  if (i < 64) bar[i] = 0u;
}
__global__ void k_deg(const int* ei, float* deg){
  int e = blockIdx.x*TPB + threadIdx.x;
  if (e < NE) atomicAdd(&deg[ei[e]], 1.0f);
}
__global__ void k_rowptr(const float* deg, int* rowptr, int* fill,
                         float* dinv, float* d2g, float* v1){
  __shared__ int part[256];
  __shared__ int off[257];
  int t = threadIdx.x;
  int base = t*8;
  int local[8];
  int s = 0;
  for (int k = 0; k < 8; k++){
    int r = base + k;
    float d = deg[r];
    dinv[r] = d > 0.f ? rsqrtf(d) : 0.f;
    d2g[r]  = rsqrtf(d + 1.f);
    v1[r]   = sqrtf(d / (float)NE);
    local[k] = s; s += (int)d;
  }
  part[t] = s;
  __syncthreads();
  if (t == 0){ off[0] = 0; for (int i = 0; i < 256; i++) off[i+1] = off[i] + part[i]; }
  __syncthreads();
  int o = off[t];
  for (int k = 0; k < 8; k++){ int v = o + local[k]; rowptr[base+k] = v; fill[base+k] = v; }
  if (t == 255) rowptr[N] = off[256];
}
__global__ void k_csr(const int* ei, int* fill, int* cols){
  int e = blockIdx.x*TPB + threadIdx.x;
  if (e < NE){
    int s = ei[e];
    int pos = atomicAdd(&fill[s], 1);
    cols[pos] = ei[NE + e];
  }
}

// ---------------- persistent mega-kernel -----------------------------------
__global__ __launch_bounds__(256) void k_mega(
    const int* __restrict__ rowptr, const int* __restrict__ cols,
    const float* __restrict__ dinv, const float* __restrict__ d2g,
    const float* __restrict__ v1, const float* __restrict__ x,
    const float* Wa1, const float* as1, const float* ad1, const float* ba1,
    const float* Wa2, const float* as2, const float* ad2, const float* ba2,
    const float* Wq, const float* bq, const float* Wk, const float* bk,
    const float* Wv, const float* bv, const float* Wo, const float* bo,
    const float* Wtq, const float* btq, const float* Wtk, const float* btk,
    const float* Wtv, const float* btv, const float* Wts, const float* bts,
    const float* Wg1, const float* bg1, const float* Wg2, const float* bg2,
    float* Qsl, float* yG, float* parts, float* parts2, float* npart,
    float* alpha, float* beta, float* zsm, float* v2,
    float* xcp, float* h8p, float* h2p, float* tkp, float* tvp, float* xtp,
    float* z16p, float* outbuf, float* scal, unsigned* mkv, int* v2i,
    unsigned* mku, int* crit, unsigned* bar){
  __shared__ __align__(16) float ybuf[N];
  __shared__ __align__(16) float yl[CH];
  __shared__ float cb[KL+2], cb2[KL+2];
  __shared__ float npl[NB];
  __shared__ float zl[KL];
  __shared__ float sh[4];
  __shared__ unsigned mkl;
  __shared__ double ta[KL], tb2[KL];
  __shared__ __align__(16) float kv[1024*10];   // MHA k/v chunk stage (40KB)
  __shared__ float rowacc[CH*6];                // MHA per-row Z + acc[5]
  __shared__ float tql[CH*5], h3l[CH*5];
  __shared__ float u_l[CH];
  __shared__ float wsm[96];
  unsigned* cnt = bar;
  unsigned* gen = bar + 32;
  unsigned phase = 0;
  const int tid = threadIdx.x, blk = blockIdx.x;
  const int wid = tid >> 6, lane = tid & 63;
  const int base = blk*CH;
  float* Qb = Qsl + (size_t)blk*KL*CH;
  float* ssq = scal + 3;

  // ==================== LANCZOS (R11-validated structure) ====================
  if (tid < CH)
    yl[tid] = (float)(wang(base + tid) & 0xffffffu) * (2.f/16777216.f) - 1.f;
  __syncthreads();
  {
    float p = (tid < CH) ? v1[base + tid]*yl[tid] : 0.f;
    float s = block_sum(p, sh);
    if (tid == 0) astoref(&parts[blk], s);
  }
  gbar(cnt, gen, &phase);
  {
    if (tid < NB) npl[tid] = aloadf(&parts[tid]);
    __syncthreads();
    float c = 0.f;
    for (int b = 0; b < NB; b++) c += npl[b];
    float acc = 0.f;
    if (tid < CH){
      float v = yl[tid] - c*v1[base + tid];
      yl[tid] = v;
      acc = v*v;
    }
    __syncthreads();
    if (tid < CH/2) astore2(yG + base + 2*tid, yl[2*tid], yl[2*tid+1]);
    float s = block_sum(acc, sh);
    if (tid == 0) astoref(&npart[blk], s);
  }
  gbar(cnt, gen, &phase);

  for (int j = 0; j < KL; j++){
    {
      for (int t = tid; t < N/2; t += TPB){
        float2 v = aload2(yG + 2*t);
        ybuf[2*t] = v.x; ybuf[2*t+1] = v.y;
      }
      if (tid < NB/2){
        float2 v = aload2(npart + 2*tid);
        npl[2*tid] = v.x; npl[2*tid+1] = v.y;
      }
    }
    __syncthreads();
    {
      float ss = 0.f;
      for (int b = 0; b < NB; b++) ss += npl[b];
      float rn = rsqrtf(ss);
      if (blk == 0 && tid == 0 && j > 0) beta[j-1] = sqrtf(ss);
      int r = tid >> 1;
      int half = tid & 1;
      int row = base + r;
      int b0 = rowptr[row], b1 = rowptr[row+1];
      float sg = 0.f;
      for (int p = b0 + half; p < b1; p += 2){
        int c = cols[p];
        sg += dinv[c]*ybuf[c];
      }
      sg += __shfl_down(sg, 1);
      if (half == 0){
        float q = rn*ybuf[row];
        Qb[(size_t)j*CH + r] = q;
        yl[r] = q - dinv[row]*rn*sg;
      }
    }
    __syncthreads();
    if (tid <= j+1){
      float d = 0.f;
      const float4* y4 = (const float4*)yl;
      if (tid <= j){
        const float4* q4 = (const float4*)(Qb + (size_t)tid*CH);
        for (int e = 0; e < CH/4; e++){
          float4 q = q4[e], yv = y4[e];
          d += q.x*yv.x + q.y*yv.y + q.z*yv.z + q.w*yv.w;
        }
      } else {
        const float4* v4 = (const float4*)(v1 + base);
        for (int e = 0; e < CH/4; e++){
          float4 q = v4[e], yv = y4[e];
          d += q.x*yv.x + q.y*yv.y + q.z*yv.z + q.w*yv.w;
        }
      }
      astoref(&parts[tid*NB + blk], d);
    }
    gbar(cnt, gen, &phase);
    if (tid <= j+1){
      const float* pr = parts + tid*NB;
      float s = 0.f;
      for (int b = 0; b < NB/2; b++){
        float2 v = aload2(pr + 2*b);
        s += v.x + v.y;
      }
      cb[tid] = s;
    }
    __syncthreads();
    {
      int e = tid >> 1, h = tid & 1;
      float a2 = 0.f;
      for (int i = h; i <= j+1; i += 2)
        a2 += cb[i] * ((i <= j) ? Qb[(size_t)i*CH + e] : v1[base + e]);
      a2 += __shfl_down(a2, 1);
      if (h == 0) yl[e] -= a2;
    }
    __syncthreads();
    if (tid <= j+1){
      float d = 0.f;
      const float4* y4 = (const float4*)yl;
      if (tid <= j){
        const float4* q4 = (const float4*)(Qb + (size_t)tid*CH);
        for (int e = 0; e < CH/4; e++){
          float4 q = q4[e], yv = y4[e];
          d += q.x*yv.x + q.y*yv.y + q.z*yv.z + q.w*yv.w;
        }
      } else {
        const float4* v4 = (const float4*)(v1 + base);
        for (int e = 0; e < CH/4; e++){
          float4 q = v4[e], yv = y4[e];
          d += q.x*yv.x + q.y*yv.y + q.z*yv.z + q.w*yv.w;
        }
      }
      astoref(&parts2[tid*NB + blk], d);
    }
    gbar(cnt, gen, &phase);
    if (tid <= j+1){
      const float* pr = parts2 + tid*NB;
      float s = 0.f;
      for (int b = 0; b < NB/2; b++){
        float2 v = aload2(pr + 2*b);
        s += v.x + v.y;
      }
      cb2[tid] = s;
    }
    __syncthreads();
    if (blk == 0 && tid == j) alpha[j] = cb[j] + cb2[j];
    float nv = 0.f;
    {
      int e = tid >> 1, h = tid & 1;
      float a2 = 0.f;
      for (int i = h; i <= j+1; i += 2)
        a2 += cb2[i] * ((i <= j) ? Qb[(size_t)i*CH + e] : v1[base + e]);
      a2 += __shfl_down(a2, 1);
      if (h == 0){
        float v = yl[e] - a2;
        yl[e] = v;
        nv = v*v;
      }
    }
    float s = block_sum(nv, sh);
    if (tid == 0) astoref(&npart[blk], s);
    if (tid < CH/2) astore2(yG + base + 2*tid, yl[2*tid], yl[2*tid+1]);
    gbar(cnt, gen, &phase);
  }

  // ---- tridiagonal eig (block 0) ----
  if (blk == 0){
    for (int i = tid; i < KL; i += TPB) ta[i] = (double)alpha[i];
    for (int i = tid; i < KL-1; i += TPB){ double bb = (double)beta[i]; tb2[i] = bb*bb; }
    __syncthreads();
    if (wid == 0){
      double th[2];
      for (int k = 1; k <= 2; k++){
        double lo = -0.5, hi = 2.5;
        for (int r = 0; r < 5; r++){
          double xx = lo + (hi - lo)*(double)(lane + 1)/65.0;
          int c = 0; double q = 1.0;
          for (int i = 0; i < KL; i++){
            double t = ta[i] - xx - ((i > 0) ? tb2[i-1]/q : 0.0);
            if (t == 0.0) t = -1e-300;
            if (t < 0.0) c++;
            q = t;
          }
          unsigned long long m = __ballot(c >= k);
          if (m == 0ULL){
            lo = lo + (hi - lo)*(64.0/65.0);
          } else {
            int f = __ffsll((long long)m) - 1;
            double nhi = lo + (hi - lo)*(double)(f + 1)/65.0;
            double nlo = lo + (hi - lo)*(double)f/65.0;
            hi = nhi; lo = nlo;
          }
        }
        th[k-1] = 0.5*(lo + hi);
      }
      double theta = (th[0] < 0.25) ? th[1] : th[0];
      if (lane == 0){
        double d[KL], dl[KL], du[KL], du2[KL], xv[KL];
        int ip[KL];
        for (int i = 0; i < KL; i++) d[i] = ta[i] - theta;
        for (int i = 0; i < KL-1; i++){ double b = (double)beta[i]; dl[i] = b; du[i] = b; }
        for (int i = 0; i < KL-1; i++){
          if (fabs(d[i]) >= fabs(dl[i])){
            ip[i] = 0;
            if (d[i] == 0.0) d[i] = 1e-30;
            double f = dl[i]/d[i]; dl[i] = f; d[i+1] -= f*du[i];
            if (i < KL-2) du2[i] = 0.0;
          } else {
            double f = d[i]/dl[i];
            d[i] = dl[i]; dl[i] = f;
            double t = du[i]; du[i] = d[i+1]; d[i+1] = t - f*d[i+1];
            if (i < KL-2){ du2[i] = du[i+1]; du[i+1] = -f*du[i+1]; }
            ip[i] = 1;
          }
        }
        if (d[KL-1] == 0.0) d[KL-1] = 1e-30;
        for (int i = 0; i < KL; i++) xv[i] = (double)(wang(1000u + i) & 0xffffu)/65536.0 - 0.5;
        for (int it = 0; it < 4; it++){
          for (int i = 0; i < KL-1; i++){
            if (ip[i] == 0) xv[i+1] -= dl[i]*xv[i];
            else { double t = xv[i]; xv[i] = xv[i+1]; xv[i+1] = t - dl[i]*xv[i]; }
          }
          xv[KL-1] /= d[KL-1];
          xv[KL-2] = (xv[KL-2] - du[KL-2]*xv[KL-1])/d[KL-2];
          for (int i = KL-3; i >= 0; i--) xv[i] = (xv[i] - du[i]*xv[i+1] - du2[i]*xv[i+2])/d[i];
          double m = 0.0;
          for (int i = 0; i < KL; i++) m = fmax(m, fabs(xv[i]));
          if (m > 0.0) for (int i = 0; i < KL; i++) xv[i] /= m;
        }
        double nrm = 0.0;
        for (int i = 0; i < KL; i++) nrm += xv[i]*xv[i];
        nrm = sqrt(nrm);
        for (int i = 0; i < KL; i++) astoref(&zsm[i], (float)(xv[i]/nrm));
      }
    }
  }
  gbar(cnt, gen, &phase);
  // ---- ritz + stats ----
  if (tid < KL) zl[tid] = aloadf(&zsm[tid]);
  __syncthreads();
  float rz = 0.f;
  if (tid < CH){
    for (int i = 0; i < KL; i++) rz += zl[i]*Qb[(size_t)i*CH + tid];
    astoref(&v2[base + tid], rz);
  }
  {
    float sq = block_sum(rz*rz, sh);
    __syncthreads();
    float av = fabsf(rz);
    for (int d2 = 1; d2 < 64; d2 <<= 1) av = fmaxf(av, __shfl_xor(av, d2));
    if ((tid & 63) == 0) sh[tid >> 6] = av;
    __syncthreads();
    if (tid == 0){
      float mb = fmaxf(fmaxf(sh[0], sh[1]), fmaxf(sh[2], sh[3]));
      atomicAdd(ssq, sq);
      atomicMax(mkv, fkey(mb));
      if (blk == 0) astorei(v2i, N);
    }
  }
  gbar(cnt, gen, &phase);
  if (tid == 0) mkl = aloadu(mkv);
  __syncthreads();
  if (tid < CH){
    float vv = aloadf(&v2[base + tid]);
    if (fkey(fabsf(vv)) == mkl) atomicMin(v2i, base + tid);
  }
  gbar(cnt, gen, &phase);
  if (blk == 0 && tid == 0){
    float s = rsqrtf(aloadf(ssq));
    int ii = aloadi(v2i);
    if (aloadf(&v2[ii]) < 0.f) s = -s;
    astoref(&scal[4], SIGN2 * s);
  }
  gbar(cnt, gen, &phase);
  // ---- scale v2; write output-2; publish xcp (stride 8) ----
  if (tid < CH){
    int i = base + tid;
    float sc = aloadf(&scal[4]);
    float l1 = aloadf(&v2[i])*sc;
    float l0 = SIGN1*v1[i];
    float c0 = x[i*3+0], c1 = x[i*3+1], c2 = x[i*3+2];
    float* o = outbuf + (size_t)N*N + 1 + (size_t)i*5;
    o[0]=c0; o[1]=c1; o[2]=c2; o[3]=l0; o[4]=l1;
    float* xp = xcp + (size_t)i*8;
    astore2(xp, c0, c1);
    astore2(xp+2, c2, l0);
    astoref(xp+4, l1);
  }
  gbar(cnt, gen, &phase);

  // ==================== PH-A: GAT1 (xcp -> h8p), Fin=5,F=8, relu ============
  if (tid < 64) wsm[tid] = (tid < 40) ? Wa1[tid]
                         : (tid < 48) ? as1[tid-40]
                         : (tid < 56) ? ad1[tid-48] : ba1[tid-56];
  __syncthreads();
  for (int rloc = wid*32; rloc < wid*32 + 32; rloc++){
    int row = base + rloc;
    float xr[5]; aload5(xcp + (size_t)row*8, xr);
    float hwr[8];
    for (int f = 0; f < 8; f++){
      float a = 0.f;
      for (int k = 0; k < 5; k++) a += xr[k]*wsm[k*8+f];
      hwr[f] = a;
    }
    float adv = 0.f, alr = 0.f;
    for (int f = 0; f < 8; f++){ adv += hwr[f]*wsm[48+f]; alr += hwr[f]*wsm[40+f]; }
    float es = alr + adv; es = es >= 0.f ? es : 0.2f*es;
    float Z = 0.f, acc[8];
    for (int f = 0; f < 8; f++) acc[f] = 0.f;
    int b0 = rowptr[row], b1 = rowptr[row+1];
    for (int p = b0 + lane; p < b1; p += 64){
      int c = cols[p];
      float xcv[5]; aload5(xcp + (size_t)c*8, xcv);
      float hc[8], al = 0.f;
      for (int f = 0; f < 8; f++){
        float a = 0.f;
        for (int k = 0; k < 5; k++) a += xcv[k]*wsm[k*8+f];
        hc[f] = a; al += a*wsm[40+f];
      }
      float e = al + adv; e = e >= 0.f ? e : 0.2f*e;
      float w = expf(e);
      Z += w;
      for (int f = 0; f < 8; f++) acc[f] += w*hc[f];
    }
    if (lane == 0){
      float w = expf(es);
      Z += w;
      for (int f = 0; f < 8; f++) acc[f] += w*hwr[f];
    }
    Z = wred(Z);
    for (int f = 0; f < 8; f++) acc[f] = wred(acc[f]);
    if (lane < 8)
      astoref(&h8p[(size_t)row*8 + lane],
              fmaxf(acc[lane]/(Z + 1e-16f) + wsm[56+lane], 0.f));
  }
  gbar(cnt, gen, &phase);

  // ==================== PH-B: GAT2 (h8p -> h2p), Fin=8,F=5 ==================
  if (tid < 55) wsm[tid] = (tid < 40) ? Wa2[tid]
                         : (tid < 45) ? as2[tid-40]
                         : (tid < 50) ? ad2[tid-45] : ba2[tid-50];
  __syncthreads();
  for (int rloc = wid*32; rloc < wid*32 + 32; rloc++){
    int row = base + rloc;
    float hr[8];
    {
      const float* p8 = h8p + (size_t)row*8;
      float2 a=aload2(p8), b=aload2(p8+2), c=aload2(p8+4), d=aload2(p8+6);
      hr[0]=a.x; hr[1]=a.y; hr[2]=b.x; hr[3]=b.y; hr[4]=c.x; hr[5]=c.y; hr[6]=d.x; hr[7]=d.y;
    }
    float hwr[5];
    for (int f = 0; f < 5; f++){
      float a = 0.f;
      for (int k = 0; k < 8; k++) a += hr[k]*wsm[k*5+f];
      hwr[f] = a;
    }
    float adv = 0.f, alr = 0.f;
    for (int f = 0; f < 5; f++){ adv += hwr[f]*wsm[45+f]; alr += hwr[f]*wsm[40+f]; }
    float es = alr + adv; es = es >= 0.f ? es : 0.2f*es;
    float Z = 0.f, acc[5];
    for (int f = 0; f < 5; f++) acc[f] = 0.f;
    int b0 = rowptr[row], b1 = rowptr[row+1];
    for (int p = b0 + lane; p < b1; p += 64){
      int c = cols[p];
      float hc8[8];
      {
        const float* p8 = h8p + (size_t)c*8;
        float2 a=aload2(p8), b=aload2(p8+2), cc=aload2(p8+4), d=aload2(p8+6);
        hc8[0]=a.x; hc8[1]=a.y; hc8[2]=b.x; hc8[3]=b.y; hc8[4]=cc.x; hc8[5]=cc.y; hc8[6]=d.x; hc8[7]=d.y;
      }
      float hc[5], al = 0.f;
      for (int f = 0; f < 5; f++){
        float a = 0.f;
        for (int k = 0; k < 8; k++) a += hc8[k]*wsm[k*5+f];
        hc[f] = a; al += a*wsm[40+f];
      }
      float e = al + adv; e = e >= 0.f ? e : 0.2f*e;
      float w = expf(e);
      Z += w;
      for (int f = 0; f < 5; f++) acc[f] += w*hc[f];
    }
    if (lane == 0){
      float w = expf(es);
      Z += w;
      for (int f = 0; f < 5; f++) acc[f] += w*hwr[f];
    }
    Z = wred(Z);
    for (int f = 0; f < 5; f++) acc[f] = wred(acc[f]);
    if (lane < 5)
      astoref(&h2p[(size_t)row*8 + lane], acc[lane]/(Z + 1e-16f) + wsm[50+lane]);
  }
  gbar(cnt, gen, &phase);

  // ==================== PH-C: MHA (chunked k/v stage) + h3 + tc projections =
  if (tid < 90) wsm[tid] = (tid < 25) ? Wk[tid]
                         : (tid < 50) ? Wv[tid-25]
                         : (tid < 55) ? bk[tid-50]
                         : (tid < 60) ? bv[tid-55]
                         : (tid < 85) ? Wq[tid-60] : bq[tid-85];
  for (int t = tid; t < CH*6; t += TPB) rowacc[t] = 0.f;
  __syncthreads();
  for (int chk = 0; chk < 2; chk++){
    for (int jl = tid; jl < 1024; jl += TPB){
      int j = chk*1024 + jl;
      float h[5]; aload5(h2p + (size_t)j*8, h);
      float* kvp = kv + jl*10;
      for (int f = 0; f < 5; f++){
        float ak = wsm[50+f], av = wsm[55+f];
        for (int k = 0; k < 5; k++){ ak += h[k]*wsm[k*5+f]; av += h[k]*wsm[25+k*5+f]; }
        kvp[f] = ak; kvp[5+f] = av;
      }
    }
    __syncthreads();
    for (int rloc = wid*32; rloc < wid*32 + 32; rloc++){
      int row = base + rloc;
      float q[5];
      {
        float h[5]; aload5(h2p + (size_t)row*8, h);
        for (int f = 0; f < 5; f++){
          float a = wsm[85+f];
          for (int k = 0; k < 5; k++) a += h[k]*wsm[60+k*5+f];
          q[f] = a;
        }
      }
      float Z = 0.f, a0=0.f,a1=0.f,a2=0.f,a3=0.f,a4=0.f;
      for (int jl = lane; jl < 1024; jl += 64){
        const float2* kp = (const float2*)(kv + jl*10);
        float2 k01=kp[0], k23=kp[1], k4v0=kp[2], v12=kp[3], v34=kp[4];
        float s = (q[0]*k01.x + q[1]*k01.y + q[2]*k23.x + q[3]*k23.y + q[4]*k4v0.x)
                  * 0.44721360f;
        float w = expf(s);
        Z += w;
        a0 += w*k4v0.y; a1 += w*v12.x; a2 += w*v12.y; a3 += w*v34.x; a4 += w*v34.y;
      }
      Z = wred(Z); a0 = wred(a0); a1 = wred(a1); a2 = wred(a2); a3 = wred(a3); a4 = wred(a4);
      if (lane == 0){
        float* ra = rowacc + rloc*6;
        ra[0]+=Z; ra[1]+=a0; ra[2]+=a1; ra[3]+=a2; ra[4]+=a3; ra[5]+=a4;
      }
    }
    __syncthreads();
  }
  // finalize: h3, tq, tk, tv per row (thread-per-row)
  if (tid < CH){
    int row = base + tid;
    const float* ra = rowacc + tid*6;
    float inv = 1.f/ra[0];
    float av5[5] = {ra[1]*inv, ra[2]*inv, ra[3]*inv, ra[4]*inv, ra[5]*inv};
    float h3[5];
    for (int f = 0; f < 5; f++){
      float a = bo[f];
      for (int k = 0; k < 5; k++) a += av5[k]*Wo[k*5+f];
      h3[f] = a;
    }
    for (int f = 0; f < 5; f++){
      h3l[tid*5+f] = h3[f];
      float aq = btq[f], ak = btk[f], avv = btv[f];
      for (int k = 0; k < 5; k++){
        aq += h3[k]*Wtq[k*5+f]; ak += h3[k]*Wtk[k*5+f]; avv += h3[k]*Wtv[k*5+f];
      }
      tql[tid*5+f] = aq;
      astoref(&tkp[(size_t)row*8 + f], ak);
      astoref(&tvp[(size_t)row*8 + f], avv);
    }
  }
  gbar(cnt, gen, &phase);

  // ==================== PH-D: TransformerConv gather + skip -> xtp ==========
  if (tid < 30) wsm[tid] = (tid < 25) ? Wts[tid] : bts[tid-25];
  __syncthreads();
  for (int rloc = wid*32; rloc < wid*32 + 32; rloc++){
    int row = base + rloc;
    float q[5];
    for (int f = 0; f < 5; f++) q[f] = tql[rloc*5+f];
    float tkr[5], tvr[5];
    aload5(tkp + (size_t)row*8, tkr);
    aload5(tvp + (size_t)row*8, tvr);
    float es = (q[0]*tkr[0]+q[1]*tkr[1]+q[2]*tkr[2]+q[3]*tkr[3]+q[4]*tkr[4])*0.44721360f;
    float Z = 0.f, acc[5];
    for (int f = 0; f < 5; f++) acc[f] = 0.f;
    int b0 = rowptr[row], b1 = rowptr[row+1];
    for (int p = b0 + lane; p < b1; p += 64){
      int c = cols[p];
      float kc[5], vc[5];
      aload5(tkp + (size_t)c*8, kc);
      aload5(tvp + (size_t)c*8, vc);
      float e = (q[0]*kc[0]+q[1]*kc[1]+q[2]*kc[2]+q[3]*kc[3]+q[4]*kc[4])*0.44721360f;
      float w = expf(e);
      Z += w;
      for (int f = 0; f < 5; f++) acc[f] += w*vc[f];
    }
    if (lane == 0){
      float w = expf(es);
      Z += w;
      for (int f = 0; f < 5; f++) acc[f] += w*tvr[f];
    }
    Z = wred(Z);
    for (int f = 0; f < 5; f++) acc[f] = wred(acc[f]);
    if (lane < 5){
      float skip = wsm[25+lane];
      for (int k = 0; k < 5; k++) skip += h3l[rloc*5+k]*wsm[k*5+lane];
      astoref(&xtp[(size_t)row*8 + lane], acc[lane]/(Z + 1e-16f) + skip);
    }
  }
  gbar(cnt, gen, &phase);

  // ==================== PH-E: GCN16 (xtp -> z16p) ===========================
  if (tid < 96) wsm[tid] = (tid < 80) ? Wg1[tid] : bg1[tid-80];
  __syncthreads();
  for (int rloc = wid*32; rloc < wid*32 + 32; rloc++){
    int row = base + rloc;
    float dr = d2g[row];
    float acc[16];
    for (int f = 0; f < 16; f++) acc[f] = 0.f;
    int b0 = rowptr[row], b1 = rowptr[row+1];
    for (int p = b0 + lane; p < b1; p += 64){
      int c = cols[p];
      float xv[5]; aload5(xtp + (size_t)c*8, xv);
      float w = d2g[c];
      for (int f = 0; f < 16; f++)
        acc[f] += w*(xv[0]*wsm[f] + xv[1]*wsm[16+f] + xv[2]*wsm[32+f]
                   + xv[3]*wsm[48+f] + xv[4]*wsm[64+f]);
    }
    if (lane == 0){
      float xv[5]; aload5(xtp + (size_t)row*8, xv);
      for (int f = 0; f < 16; f++)
        acc[f] += dr*(xv[0]*wsm[f] + xv[1]*wsm[16+f] + xv[2]*wsm[32+f]
                    + xv[3]*wsm[48+f] + xv[4]*wsm[64+f]);
    }
    for (int f = 0; f < 16; f++) acc[f] = wred(acc[f]);
    if (lane < 16)
      astoref(&z16p[(size_t)row*16 + lane],
              fmaxf(dr*acc[lane] + wsm[80+lane], 0.f));
  }
  gbar(cnt, gen, &phase);

  // ==================== PH-F: GCN1 -> u, global max =========================
  if (tid < 16) wsm[tid] = Wg2[tid];
  if (blk == 0 && tid == 0) astorei(crit, N);
  __syncthreads();
  for (int rloc = wid*32; rloc < wid*32 + 32; rloc++){
    int row = base + rloc;
    float s = 0.f;
    int b0 = rowptr[row], b1 = rowptr[row+1];
    for (int p = b0 + lane; p < b1; p += 64){
      int c = cols[p];
      const float* zr = z16p + (size_t)c*16;
      float p1c = 0.f;
      for (int k = 0; k < 16; k += 2){
        float2 z = aload2(zr + k);
        p1c += z.x*wsm[k] + z.y*wsm[k+1];
      }
      s += d2g[c]*p1c;
    }
    if (lane == 0){
      const float* zr = z16p + (size_t)row*16;
      float p1c = 0.f;
      for (int k = 0; k < 16; k += 2){
        float2 z = aload2(zr + k);
        p1c += z.x*wsm[k] + z.y*wsm[k+1];
      }
      s += d2g[row]*p1c;
    }
    s = wred(s);
    if (lane == 0){
      float uv = d2g[row]*s + bg2[0];
      u_l[rloc] = uv;
      atomicMax(mku, fkey(uv));
    }
  }
  gbar(cnt, gen, &phase);

  // ==================== PH-G: crit + bonus ==================================
  {
    unsigned mk = aloadu(mku);
    if (tid < CH){
      if (fkey(u_l[tid]) == mk) atomicMin(crit, base + tid);
    }
    if (blk == 0 && tid == 0){
      float um = fkeyinv(mk);
      scal[5] = ((0.8f - um) < 0.2f) ? 10.f : 0.f;
    }
  }
}

// ---------------- final logits + value (hm fused in LDS) -------------------
__global__ __launch_bounds__(256) void k_logits(const float* xtp,
    const float* W1, const float* b1, const float* W2,
    const float* b2, const float* mask, const float* Wc, const int* crit,
    const float* bonus, float* out, float* vacc){
  __shared__ float sh[4];
  __shared__ float hml[64];
  int i = blockIdx.y;
  if (threadIdx.x < 64){
    const float* xr = xtp + (size_t)i*8;
    float acc = b1[threadIdx.x];
    for (int k = 0; k < 5; k++) acc += xr[k]*W1[k*64 + threadIdx.x];
    hml[threadIdx.x] = fmaxf(acc, 0.f);
  }
  __syncthreads();
  int j = blockIdx.x*TPB + threadIdx.x;
  float acc = b2[j];
  for (int c = 0; c < 64; c++) acc += hml[c]*W2[c*N + j];
  if (i == crit[0]) acc += bonus[0];
  out[(size_t)i*N + j] = acc*mask[j];
  float s = block_sum(acc*Wc[j], sh);
  if (threadIdx.x == 0) atomicAdd(vacc, s);
}
__global__ void k_value(const float* vacc, const float* bc, float* out){
  out[(size_t)N*N] = vacc[0]/(float)N + bc[0];
}

// ---------------------------------------------------------------------------
extern "C" void kernel_launch(void* const* d_in, const int* in_sizes, int n_in,
                              void* d_out, int out_size, void* d_ws, size_t ws_size,
                              hipStream_t stream){
  const float* x    = (const float*)d_in[0];
  const int*   ei   = (const int*)d_in[1];
  const float* mask = (const float*)d_in[2];
  const float* Wg1=(const float*)d_in[3];  const float* bg1=(const float*)d_in[4];
  const float* Wg2=(const float*)d_in[5];  const float* bg2=(const float*)d_in[6];
  const float* Wa1=(const float*)d_in[7];  const float* as1=(const float*)d_in[8];
  const float* ad1=(const float*)d_in[9];  const float* ba1=(const float*)d_in[10];
  const float* Wa2=(const float*)d_in[11]; const float* as2=(const float*)d_in[12];
  const float* ad2=(const float*)d_in[13]; const float* ba2=(const float*)d_in[14];
  const float* Wq=(const float*)d_in[15];  const float* bq=(const float*)d_in[16];
  const float* Wk=(const float*)d_in[17];  const float* bk=(const float*)d_in[18];
  const float* Wv=(const float*)d_in[19];  const float* bv=(const float*)d_in[20];
  const float* Wo=(const float*)d_in[21];  const float* bo=(const float*)d_in[22];
  const float* Wtq=(const float*)d_in[23]; const float* btq=(const float*)d_in[24];
  const float* Wtk=(const float*)d_in[25]; const float* btk=(const float*)d_in[26];
  const float* Wtv=(const float*)d_in[27]; const float* btv=(const float*)d_in[28];
  const float* Wts=(const float*)d_in[29]; const float* bts=(const float*)d_in[30];
  const float* W1=(const float*)d_in[31];  const float* b1=(const float*)d_in[32];
  const float* W2=(const float*)d_in[33];  const float* b2=(const float*)d_in[34];
  const float* Wc=(const float*)d_in[35];  const float* bc=(const float*)d_in[36];
  float* out = (float*)d_out;
  float* ws  = (float*)d_ws;

  // ---- ws layout (floats) ----
  float* deg  = ws;           float* dinv = ws + 2048;
  float* d2g  = ws + 4096;    float* v1   = ws + 6144;
  float* y    = ws + 8192;    float* v2   = ws + 10240;
  float* alpha= ws + 12448;   float* beta = ws + 12576;
  float* scal = ws + 12704;                        // 16 scalar slots
  unsigned* mku = (unsigned*)(scal + 8);
  unsigned* mkv = (unsigned*)(scal + 9);
  int* crit = (int*)(scal + 10);
  int* v2i  = (int*)(scal + 11);
  float* zsm  = ws + 12720;                        // 128
  float* xtp  = ws + 20000;                        // 16384 (stride 8) -- in WS:
                                                   // read by k_logits while it
                                                   // writes out[0..N^2) (R13 bug fix)

  // ---- big scratch carved from d_out[0..N*N): consumed before k_logits ----
  float* Qsl  = out;                    // NB*KL*CH = 131072
  float* xcp  = out + 140000;           // stride 8
  float* h8p  = out + 160000;
  float* h2p  = out + 180000;
  float* tkp  = out + 200000;
  float* tvp  = out + 220000;
  float* z16p = out + 260000;           // stride 16
  unsigned* bar = (unsigned*)(out + 300000);  // 64
  int* rowptr = (int*)(out + 300128);   // 2049
  int* fill   = (int*)(out + 302592);   // 2048
  int* cols   = (int*)(out + 306000);   // 131072 -> ends 437072
  float* parts  = out + 440000;
  float* parts2 = out + 442000;
  float* npart  = out + 444000;

  // ================= setup =================
  k_init<<<8, TPB, 0, stream>>>(deg, scal, bar);
  k_deg<<<NE/TPB, TPB, 0, stream>>>(ei, deg);
  k_rowptr<<<1, TPB, 0, stream>>>(deg, rowptr, fill, dinv, d2g, v1);
  k_csr<<<NE/TPB, TPB, 0, stream>>>(ei, fill, cols);

  // ================= mega-kernel: Lanczos + full GNN pipeline ==============
  k_mega<<<NB, TPB, 0, stream>>>(rowptr, cols, dinv, d2g, v1, x,
      Wa1, as1, ad1, ba1, Wa2, as2, ad2, ba2,
      Wq, bq, Wk, bk, Wv, bv, Wo, bo,
      Wtq, btq, Wtk, btk, Wtv, btv, Wts, bts,
      Wg1, bg1, Wg2, bg2,
      Qsl, y, parts, parts2, npart, alpha, beta, zsm, v2,
      xcp, h8p, h2p, tkp, tvp, xtp, z16p,
      out, scal, mkv, v2i, mku, crit, bar);

  // ================= logits (hm fused) + value =================
  k_logits<<<dim3(8, N), TPB, 0, stream>>>(xtp, W1, b1, W2, b2, mask, Wc, crit,
                                           scal + 5, out, scal + 6);
  k_value<<<1, 1, 0, stream>>>(scal + 6, bc, out);
}